// Round 17
// baseline (282.710 us; speedup 1.0000x reference)
//
#include <hip/hip_runtime.h>

// AdaptiveConv: out[b,c,h,w] = sum_{idx<25} x[b,c,h+idx/5, w+idx%5] * kernel[b,idx,h,w]
// Shapes: x (8,64,260,260) f32, kernel (8,25,256,256) f32, out (8,64,256,256) f32.
//
// R16: falsified so far: occupancy (R9->R10 null), tap traffic (R10 vs R15
// null), tap prefetch (sunk, R11/R14), stage/compute overlap (R13 regressed).
// Invariant across all: 10 LDS-reads per output-f4 (x re-read per (i,ch)).
// Fix: ROW-PAIR threads + x-row-major loop. Thread owns output rows (r,r+1);
// loop t over x-rows: x row t (2 ds_read_b128) feeds output r at i=t AND
// output r+1 at i=t-1 -> 40 FMAs per read pair (2x). LDS reads 10 -> 6 per
// output-f4. Taps (r,t),(r+1,t-1) = 10 f4 loaded fresh per t (streamed, not
// loop-invariant -> no sink risk). Tile 16 rows x 128 cols x 4 ch = 43.5 KB
// -> 3 blk/CU. R15's LDS row stride (136 words, 2-way-free) + staging kept.

constexpr int K  = 5;
constexpr int B  = 8;
constexpr int C  = 64;
constexpr int H  = 256;
constexpr int W  = 256;
constexpr int HX = H + K - 1;   // 260
constexpr int WX = W + K - 1;   // 260

constexpr int CH  = 4;          // channels per block
constexpr int NCG = C / CH;     // 16 channel groups
constexpr int HPB = 16;         // output rows per block
constexpr int NHB = H / HPB;    // 16 h-blocks
constexpr int WPB = 128;        // output cols per block
constexpr int NWS = W / WPB;    // 2 width splits
constexpr int NWG = NCG * NWS * NHB * B;  // 4096 blocks

constexpr int XR   = HPB + K - 1;   // 20 staged x-rows
constexpr int ROWF = 136;           // floats per LDS row (132 used + 4 pad)
constexpr int SF4  = 33;            // staged f4 per row
constexpr int STAGE_F4 = CH * XR * SF4;  // 2640 f4
// LDS: 4 ch x 20 rows x 136 floats x 4B = 43,520 B -> 3 blocks/CU.

typedef float f4 __attribute__((ext_vector_type(4)));

__global__ __launch_bounds__(256, 3)
void adaptive_conv_kernel(const float* __restrict__ x,
                          const float* __restrict__ kern,
                          float* __restrict__ out) {
    __shared__ float xs[CH][XR][ROWF];

    // XCD-aware swizzle (bijective: NWG % 8 == 0); cg fastest so the 16 blocks
    // sharing one kern tile run consecutively on one XCD (R8, FETCH-verified).
    const int k    = blockIdx.x;
    const int orig = (k & 7) * (NWG / 8) + (k >> 3);
    const int cg   = orig & (NCG - 1);          // channel group (fastest)
    const int ws   = (orig >> 4) & (NWS - 1);   // width split
    const int hblk = (orig >> 5) & (NHB - 1);   // h-block
    const int b    = orig >> 9;                 // batch (slowest)

    const int tid = threadIdx.x;
    const int cp  = tid & 31;               // col group (4 cols, 16B aligned)
    const int rp  = tid >> 5;               // 0..7: row pair within block
    const int w0l = cp * 4;                 // local col base
    const int wg0 = ws * WPB;               // 0 or 128
    const int h0  = hblk * HPB + rp * 2;    // first of my 2 output rows
    const int c0  = cg * CH;                // channel base

    const size_t xplane = (size_t)HX * WX;

    // ---- stage x[b, c0:c0+4, hblk*16 : +20, wg0 : wg0+132] -> LDS ----
    // 2640 f4 over 256 threads = 11 guarded sweeps. Row stride 34 f4
    // (136 floats): R15-proven low-conflict. All addresses 16B-aligned.
    {
        const float* xg = x + ((size_t)b * C + c0) * xplane
                            + (size_t)(hblk * HPB) * WX + wg0;
        #pragma unroll
        for (int it = 0; it < 11; ++it) {
            const int idx = it * 256 + tid;
            if (idx < STAGE_F4) {
                const int ch  = idx / (XR * SF4);     // /660 -> magic-mul
                const int rem = idx - ch * (XR * SF4);
                const int rr  = rem / SF4;            // /33
                const int s   = rem - rr * SF4;
                f4 v = *(const f4*)(xg + (size_t)ch * xplane + rr * WX + s * 4);
                *(f4*)&xs[ch][rr][s * 4] = v;
            }
        }
    }
    __syncthreads();

    // Tap bases for my two output rows (row r = h0, row r+1 = h0+1).
    const float* kb = kern + (size_t)b * (K * K * H * W)
                           + (size_t)h0 * W + wg0 + w0l;

    f4 acc[CH][2];
    #pragma unroll
    for (int ch = 0; ch < CH; ++ch) {
        acc[ch][0] = (f4)0.0f;
        acc[ch][1] = (f4)0.0f;
    }

    // x-row-major loop: x local row (rp*2 + t) serves output r at i=t and
    // output r+1 at i=t-1 -> one read pair feeds 40 FMAs (t=1..4).
    #pragma unroll
    for (int t = 0; t < K + 1; ++t) {
        f4 t0[K], t1[K];
        if (t < K) {            // taps (row r, i=t) — static guard, unrolled
            #pragma unroll
            for (int j = 0; j < K; ++j)
                t0[j] = *(const f4*)(kb + (size_t)(t * K + j) * (H * W));
        }
        if (t >= 1) {           // taps (row r+1, i=t-1)
            #pragma unroll
            for (int j = 0; j < K; ++j)
                t1[j] = *(const f4*)(kb + W + (size_t)((t - 1) * K + j) * (H * W));
        }

        #pragma unroll
        for (int ch = 0; ch < CH; ++ch) {
            // x local row rp*2+t, cols w0l..w0l+7: two b128, 2-way-free banks.
            const float* xr_ = &xs[ch][rp * 2 + t][w0l];
            f4 xa  = *(const f4*)(xr_);
            f4 xb_ = *(const f4*)(xr_ + 4);
            float xsg[8] = {xa.x, xa.y, xa.z, xa.w, xb_.x, xb_.y, xb_.z, xb_.w};

            if (t < K) {
                #pragma unroll
                for (int j = 0; j < K; ++j) {      // static indices only
                    acc[ch][0].x = fmaf(xsg[j + 0], t0[j].x, acc[ch][0].x);
                    acc[ch][0].y = fmaf(xsg[j + 1], t0[j].y, acc[ch][0].y);
                    acc[ch][0].z = fmaf(xsg[j + 2], t0[j].z, acc[ch][0].z);
                    acc[ch][0].w = fmaf(xsg[j + 3], t0[j].w, acc[ch][0].w);
                }
            }
            if (t >= 1) {
                #pragma unroll
                for (int j = 0; j < K; ++j) {
                    acc[ch][1].x = fmaf(xsg[j + 0], t1[j].x, acc[ch][1].x);
                    acc[ch][1].y = fmaf(xsg[j + 1], t1[j].y, acc[ch][1].y);
                    acc[ch][1].z = fmaf(xsg[j + 2], t1[j].z, acc[ch][1].z);
                    acc[ch][1].w = fmaf(xsg[j + 3], t1[j].w, acc[ch][1].w);
                }
            }
        }
    }

    float* ob = out + ((size_t)b * C + c0) * (H * W) + (size_t)h0 * W + wg0 + w0l;
    #pragma unroll
    for (int ch = 0; ch < CH; ++ch) {
        // out written once, never read: bypass caches (keep x+kern resident).
        __builtin_nontemporal_store(acc[ch][0], (f4*)(ob + (size_t)ch * (H * W)));
        __builtin_nontemporal_store(acc[ch][1], (f4*)(ob + (size_t)ch * (H * W) + W));
    }
}

extern "C" void kernel_launch(void* const* d_in, const int* in_sizes, int n_in,
                              void* d_out, int out_size, void* d_ws, size_t ws_size,
                              hipStream_t stream) {
    const float* x    = (const float*)d_in[0];
    const float* kern = (const float*)d_in[1];
    float*       out  = (float*)d_out;

    dim3 grid(NWG);      // 4096 blocks, 1D; decode + swizzle in-kernel
    dim3 block(256);     // 8 row-pairs x 32 col-groups
    adaptive_conv_kernel<<<grid, block, 0, stream>>>(x, kern, out);
}

// Round 18
// 74.078 us; speedup vs baseline: 3.8164x; 3.8164x over previous
//
#include <hip/hip_runtime.h>

// AdaptiveConv: out[b,c,h,w] = sum_{idx<25} x[b,c,h+idx/5, w+idx%5] * kernel[b,idx,h,w]
// Shapes: x (8,64,260,260) f32, kernel (8,25,256,256) f32, out (8,64,256,256) f32.
//
// R17: R16's row-pair theory never ran — it spilled (WRITE 581MB, VGPR 84).
// Compiler signature (R6 == R16): under __launch_bounds__(256,3) the allocator
// caps near 84 VGPR and spills; under (256,2) it grows to 128 cleanly (R13).
// The row-pair body needs ~95 live regs (acc 32 + taps 40 + x 8 + addr), legal
// at 3 blk/CU (LDS 43.5KB is the residency cap, VGPR<=170 allows 3 waves/SIMD).
// R17 = R16 body EXACTLY, one change: __launch_bounds__(256,2).
// Row-pair recap: thread owns output rows (r,r+1); x-row t feeds row r at tap
// row i=t and row r+1 at i=t-1 -> one ds_read_b128 pair serves 40 FMAs; LDS
// reads per output-f4 drop 10 -> 6. Taps are per-t (not loop-invariant) so
// they cannot be sunk — only spill could kill this, and (256,2) removes it.

constexpr int K  = 5;
constexpr int B  = 8;
constexpr int C  = 64;
constexpr int H  = 256;
constexpr int W  = 256;
constexpr int HX = H + K - 1;   // 260
constexpr int WX = W + K - 1;   // 260

constexpr int CH  = 4;          // channels per block
constexpr int NCG = C / CH;     // 16 channel groups
constexpr int HPB = 16;         // output rows per block
constexpr int NHB = H / HPB;    // 16 h-blocks
constexpr int WPB = 128;        // output cols per block
constexpr int NWS = W / WPB;    // 2 width splits
constexpr int NWG = NCG * NWS * NHB * B;  // 4096 blocks

constexpr int XR   = HPB + K - 1;   // 20 staged x-rows
constexpr int ROWF = 136;           // floats per LDS row (132 used + 4 pad)
constexpr int SF4  = 33;            // staged f4 per row
constexpr int STAGE_F4 = CH * XR * SF4;  // 2640 f4
// LDS: 4 ch x 20 rows x 136 floats x 4B = 43,520 B -> 3 blocks/CU.

typedef float f4 __attribute__((ext_vector_type(4)));

__global__ __launch_bounds__(256, 2)
void adaptive_conv_kernel(const float* __restrict__ x,
                          const float* __restrict__ kern,
                          float* __restrict__ out) {
    __shared__ float xs[CH][XR][ROWF];

    // XCD-aware swizzle (bijective: NWG % 8 == 0); cg fastest so the 16 blocks
    // sharing one kern tile run consecutively on one XCD (R8, FETCH-verified).
    const int k    = blockIdx.x;
    const int orig = (k & 7) * (NWG / 8) + (k >> 3);
    const int cg   = orig & (NCG - 1);          // channel group (fastest)
    const int ws   = (orig >> 4) & (NWS - 1);   // width split
    const int hblk = (orig >> 5) & (NHB - 1);   // h-block
    const int b    = orig >> 9;                 // batch (slowest)

    const int tid = threadIdx.x;
    const int cp  = tid & 31;               // col group (4 cols, 16B aligned)
    const int rp  = tid >> 5;               // 0..7: row pair within block
    const int w0l = cp * 4;                 // local col base
    const int wg0 = ws * WPB;               // 0 or 128
    const int h0  = hblk * HPB + rp * 2;    // first of my 2 output rows
    const int c0  = cg * CH;                // channel base

    const size_t xplane = (size_t)HX * WX;

    // ---- stage x[b, c0:c0+4, hblk*16 : +20, wg0 : wg0+132] -> LDS ----
    // 2640 f4 over 256 threads = 11 guarded sweeps. Row stride 34 f4
    // (136 floats): R15-proven low-conflict. All addresses 16B-aligned.
    {
        const float* xg = x + ((size_t)b * C + c0) * xplane
                            + (size_t)(hblk * HPB) * WX + wg0;
        #pragma unroll
        for (int it = 0; it < 11; ++it) {
            const int idx = it * 256 + tid;
            if (idx < STAGE_F4) {
                const int ch  = idx / (XR * SF4);     // /660 -> magic-mul
                const int rem = idx - ch * (XR * SF4);
                const int rr  = rem / SF4;            // /33
                const int s   = rem - rr * SF4;
                f4 v = *(const f4*)(xg + (size_t)ch * xplane + rr * WX + s * 4);
                *(f4*)&xs[ch][rr][s * 4] = v;
            }
        }
    }
    __syncthreads();

    // Tap bases for my two output rows (row r = h0, row r+1 = h0+1).
    const float* kb = kern + (size_t)b * (K * K * H * W)
                           + (size_t)h0 * W + wg0 + w0l;

    f4 acc[CH][2];
    #pragma unroll
    for (int ch = 0; ch < CH; ++ch) {
        acc[ch][0] = (f4)0.0f;
        acc[ch][1] = (f4)0.0f;
    }

    // x-row-major loop: x local row (rp*2 + t) serves output r at i=t and
    // output r+1 at i=t-1 -> one read pair feeds 40 FMAs (t=1..4).
    #pragma unroll
    for (int t = 0; t < K + 1; ++t) {
        f4 t0[K], t1[K];
        if (t < K) {            // taps (row r, i=t) — static guard, unrolled
            #pragma unroll
            for (int j = 0; j < K; ++j)
                t0[j] = *(const f4*)(kb + (size_t)(t * K + j) * (H * W));
        }
        if (t >= 1) {           // taps (row r+1, i=t-1)
            #pragma unroll
            for (int j = 0; j < K; ++j)
                t1[j] = *(const f4*)(kb + W + (size_t)((t - 1) * K + j) * (H * W));
        }

        #pragma unroll
        for (int ch = 0; ch < CH; ++ch) {
            // x local row rp*2+t, cols w0l..w0l+7: two b128, 2-way-free banks.
            const float* xr_ = &xs[ch][rp * 2 + t][w0l];
            f4 xa  = *(const f4*)(xr_);
            f4 xb_ = *(const f4*)(xr_ + 4);
            float xsg[8] = {xa.x, xa.y, xa.z, xa.w, xb_.x, xb_.y, xb_.z, xb_.w};

            if (t < K) {
                #pragma unroll
                for (int j = 0; j < K; ++j) {      // static indices only
                    acc[ch][0].x = fmaf(xsg[j + 0], t0[j].x, acc[ch][0].x);
                    acc[ch][0].y = fmaf(xsg[j + 1], t0[j].y, acc[ch][0].y);
                    acc[ch][0].z = fmaf(xsg[j + 2], t0[j].z, acc[ch][0].z);
                    acc[ch][0].w = fmaf(xsg[j + 3], t0[j].w, acc[ch][0].w);
                }
            }
            if (t >= 1) {
                #pragma unroll
                for (int j = 0; j < K; ++j) {
                    acc[ch][1].x = fmaf(xsg[j + 0], t1[j].x, acc[ch][1].x);
                    acc[ch][1].y = fmaf(xsg[j + 1], t1[j].y, acc[ch][1].y);
                    acc[ch][1].z = fmaf(xsg[j + 2], t1[j].z, acc[ch][1].z);
                    acc[ch][1].w = fmaf(xsg[j + 3], t1[j].w, acc[ch][1].w);
                }
            }
        }
    }

    float* ob = out + ((size_t)b * C + c0) * (H * W) + (size_t)h0 * W + wg0 + w0l;
    #pragma unroll
    for (int ch = 0; ch < CH; ++ch) {
        // out written once, never read: bypass caches (keep x+kern resident).
        __builtin_nontemporal_store(acc[ch][0], (f4*)(ob + (size_t)ch * (H * W)));
        __builtin_nontemporal_store(acc[ch][1], (f4*)(ob + (size_t)ch * (H * W) + W));
    }
}

extern "C" void kernel_launch(void* const* d_in, const int* in_sizes, int n_in,
                              void* d_out, int out_size, void* d_ws, size_t ws_size,
                              hipStream_t stream) {
    const float* x    = (const float*)d_in[0];
    const float* kern = (const float*)d_in[1];
    float*       out  = (float*)d_out;

    dim3 grid(NWG);      // 4096 blocks, 1D; decode + swizzle in-kernel
    dim3 block(256);     // 8 row-pairs x 32 col-groups
    adaptive_conv_kernel<<<grid, block, 0, stream>>>(x, kern, out);
}

// Round 19
// 67.310 us; speedup vs baseline: 4.2001x; 1.1005x over previous
//
#include <hip/hip_runtime.h>

// AdaptiveConv: out[b,c,h,w] = sum_{idx<25} x[b,c,h+idx/5, w+idx%5] * kernel[b,idx,h,w]
// Shapes: x (8,64,260,260) f32, kernel (8,25,256,256) f32, out (8,64,256,256) f32.
//
// R19: isolate OCCUPANCY with the proven-best inner loop. R9->R10's "occupancy
// null" was confounded (CH changed too). No variant has run above 42% occ; all
// plateau at 65-66us, VALUBusy ~30% (timed-scaled), classic under-hidden
// latency. This round: R10's exact body (CH=4, 5-tap-f4 rows, 2 ds_read_b128
// + 20 FMA per (i,ch)), tile shrunk to 4ch x 12rows x 136f = 26.1KB LDS ->
// 6 blocks/CU = 24 waves/CU (75%), VGPR must stay <=85 (R10 body = 64).
//  - block 256 = 8 rows x 32 col-groups; thread = 4 cols x 1 row x 4 ch.
//  - W-split 128: halo 1.55x -> x-fill ~215MB; taps 840MB L2 (R10-proven).
//  - R8 XCD swizzle, cg fastest: 16 tap-sharers consecutive per XCD.
// Pre-commit: occ>=60% and dur flat 64-67 -> TLP falsified -> ROOFLINE call.

constexpr int K  = 5;
constexpr int B  = 8;
constexpr int C  = 64;
constexpr int H  = 256;
constexpr int W  = 256;
constexpr int HX = H + K - 1;   // 260
constexpr int WX = W + K - 1;   // 260

constexpr int CH  = 4;          // channels per block (R10-proven)
constexpr int NCG = C / CH;     // 16 channel groups
constexpr int HPB = 8;          // output rows per block
constexpr int NHB = H / HPB;    // 32 h-blocks
constexpr int WPB = 128;        // output cols per block
constexpr int NWS = W / WPB;    // 2 width splits
constexpr int NWG = NCG * NWS * NHB * B;  // 8192 blocks

constexpr int XR   = HPB + K - 1;   // 12 staged x-rows
constexpr int ROWF = 136;           // floats per LDS row (132 used + 4 pad)
constexpr int SF4  = 33;            // staged f4 per row
constexpr int STAGE_F4 = CH * XR * SF4;  // 1584 f4
// LDS: 4 ch x 12 rows x 136 floats x 4B = 26,112 B -> 6 blocks/CU.

typedef float f4 __attribute__((ext_vector_type(4)));

__global__ __launch_bounds__(256, 4)
void adaptive_conv_kernel(const float* __restrict__ x,
                          const float* __restrict__ kern,
                          float* __restrict__ out) {
    __shared__ float xs[CH][XR][ROWF];

    // XCD-aware swizzle (bijective: NWG % 8 == 0); cg fastest so the 16 blocks
    // sharing one kern tile run consecutively on one XCD (R8, FETCH-verified).
    const int k    = blockIdx.x;
    const int orig = (k & 7) * (NWG / 8) + (k >> 3);
    const int cg   = orig & (NCG - 1);          // channel group (fastest)
    const int ws   = (orig >> 4) & (NWS - 1);   // width split
    const int hblk = (orig >> 5) & (NHB - 1);   // h-block
    const int b    = orig >> 10;                // batch (slowest)

    const int tid = threadIdx.x;
    const int r   = tid >> 5;               // 0..7: output row within block
    const int cp  = tid & 31;               // col group (4 cols, 16B aligned)
    const int w0l = cp * 4;                 // local col base
    const int wg0 = ws * WPB;               // 0 or 128
    const int h   = hblk * HPB + r;         // output row
    const int c0  = cg * CH;                // channel base

    const size_t xplane = (size_t)HX * WX;

    // ---- stage x[b, c0:c0+4, hblk*8 : +12, wg0 : wg0+132] -> LDS (26.1 KB) ----
    // 1584 f4 over 256 threads = 7 guarded sweeps. Row stride 34 f4 (136
    // floats): R15-proven low-conflict. Max row = 31*8+11 = 259, max col =
    // 128+131 = 259: in-bounds by construction. All addresses 16B-aligned.
    {
        const float* xg = x + ((size_t)b * C + c0) * xplane
                            + (size_t)(hblk * HPB) * WX + wg0;
        #pragma unroll
        for (int it = 0; it < 7; ++it) {
            const int idx = it * 256 + tid;
            if (idx < STAGE_F4) {
                const int ch  = idx / (XR * SF4);     // /396 -> magic-mul
                const int rem = idx - ch * (XR * SF4);
                const int rr  = rem / SF4;            // /33
                const int s   = rem - rr * SF4;
                f4 v = *(const f4*)(xg + (size_t)ch * xplane + rr * WX + s * 4);
                *(f4*)&xs[ch][rr][s * 4] = v;
            }
        }
    }
    __syncthreads();

    const float* kb = kern + (size_t)b * (K * K * H * W)
                           + (size_t)h * W + wg0 + w0l;

    f4 acc[CH];
    #pragma unroll
    for (int ch = 0; ch < CH; ++ch) acc[ch] = (f4)0.0f;

    #pragma unroll
    for (int i = 0; i < K; ++i) {
        // Tap row i: 5 f4 (my 4 cols, j=0..4), reused across 4 channels.
        f4 t[K];
        #pragma unroll
        for (int j = 0; j < K; ++j) {
            t[j] = *(const f4*)(kb + (size_t)(i * K + j) * (H * W));
        }

        #pragma unroll
        for (int ch = 0; ch < CH; ++ch) {
            // x row (r+i), local cols w0l..w0l+7 from LDS: two b128 reads,
            // contiguous 16B/lane within each 32-lane row-slice: conflict-free.
            const float* xr_ = &xs[ch][r + i][w0l];
            f4 xa  = *(const f4*)(xr_);
            f4 xcv = *(const f4*)(xr_ + 4);
            float xsg[8] = {xa.x, xa.y, xa.z, xa.w, xcv.x, xcv.y, xcv.z, xcv.w};

            #pragma unroll
            for (int j = 0; j < K; ++j) {      // static indices only (rule #20)
                acc[ch].x = fmaf(xsg[j + 0], t[j].x, acc[ch].x);
                acc[ch].y = fmaf(xsg[j + 1], t[j].y, acc[ch].y);
                acc[ch].z = fmaf(xsg[j + 2], t[j].z, acc[ch].z);
                acc[ch].w = fmaf(xsg[j + 3], t[j].w, acc[ch].w);
            }
        }
    }

    float* ob = out + ((size_t)b * C + c0) * (H * W) + (size_t)h * W + wg0 + w0l;
    #pragma unroll
    for (int ch = 0; ch < CH; ++ch) {
        // out written once, never read: bypass caches (keep x+kern resident).
        __builtin_nontemporal_store(acc[ch], (f4*)(ob + (size_t)ch * (H * W)));
    }
}

extern "C" void kernel_launch(void* const* d_in, const int* in_sizes, int n_in,
                              void* d_out, int out_size, void* d_ws, size_t ws_size,
                              hipStream_t stream) {
    const float* x    = (const float*)d_in[0];
    const float* kern = (const float*)d_in[1];
    float*       out  = (float*)d_out;

    dim3 grid(NWG);      // 8192 blocks, 1D; decode + swizzle in-kernel
    dim3 block(256);     // 8 rows x 32 col-groups
    adaptive_conv_kernel<<<grid, block, 0, stream>>>(x, kern, out);
}